// Round 3
// baseline (251.951 us; speedup 1.0000x reference)
//
#include <hip/hip_runtime.h>
#include <hip/hip_bf16.h>
#include <cmath>

#define V 8192
#define NREF 262144
#define NALT 131072
#define NREADS (NREF + NALT)
#define FR 11
#define FI 9
#define HH 256
#define MAX_ALT 10

#define TILE_R 128   // phi rows per block
#define TILE_V 16    // rho variants per block (r15: halved for 2 blocks/CU)

#define HPITCH 264   // sH pitch (shorts): 528 B rows, 16B-aligned
#define RBPITCH 40   // sRB pitch (shorts)
#define CPITCH 776   // sC pitch (shorts)
#define APITCH 264   // sA1/sAgg pitch

typedef short bf16x8 __attribute__((ext_vector_type(8)));
typedef float f32x4  __attribute__((ext_vector_type(4)));

#define NLOG2E (-1.442695041f)

__device__ __forceinline__ float sigmoidf_(float x) {
    return __builtin_amdgcn_rcpf(1.0f + __expf(-x));
}
__device__ __forceinline__ float lrelu_(float x) {
    return fmaxf(x, 0.01f * x);
}
__device__ __forceinline__ unsigned short f2bf_(float f) {
    unsigned int u = __float_as_uint(f);
    u += 0x7FFFu + ((u >> 16) & 1u);
    return (unsigned short)(u >> 16);
}
__device__ __forceinline__ float bf2f_(unsigned short b) {
    return __uint_as_float(((unsigned int)b) << 16);
}
__device__ __forceinline__ unsigned int pk2bf_(float a, float b) {
    union { __hip_bfloat162 h2; unsigned int u; } cvt;
    cvt.h2 = __float22bfloat162_rn(make_float2(a, b));
    return cvt.u;
}
__device__ __forceinline__ float lo16f_(unsigned int u) {   // bf16 in low 16 -> f32
    return __uint_as_float(u << 16);
}
__device__ __forceinline__ float hi16f_(unsigned int u) {   // bf16 in high 16 -> f32
    return __uint_as_float(u & 0xFFFF0000u);
}

// ---------------------------------------------------------------------------
// Fused prep: 4 transposes (f32->bf16) + phi-W0 pack + accumulator zeroing.
// w1t_phi (phi_W1 transpose) is pre-scaled by -log2(e) so that phi GEMM2
// produces -x*log2(e) directly and sigmoid becomes rcp(1 + exp2(y)).
// ---------------------------------------------------------------------------
__global__ __launch_bounds__(256) void prep_kernel(
    const float* __restrict__ phi_W1, const float* __restrict__ rho_W0,
    const float* __restrict__ rho_W1, const float* __restrict__ out_W1,
    const float* __restrict__ phi_W0,
    unsigned short* __restrict__ w1t_phi, unsigned short* __restrict__ w0t,
    unsigned short* __restrict__ w1rt, unsigned short* __restrict__ whT,
    unsigned short* __restrict__ w0pT, float* __restrict__ zbase)
{
    __shared__ unsigned short sT[32][33];
    const int b = blockIdx.x;
    const int t = threadIdx.x;
    if (b < 512) {
        const float* src; unsigned short* dst; int R, C, bx, by;
        float scl = 1.0f;
        if (b < 64)       { src = phi_W1; dst = w1t_phi; R = 256; C = 256; bx = b & 7; by = b >> 3; scl = NLOG2E; }
        else if (b < 256) { int i = b - 64;  src = rho_W0; dst = w0t;  R = 768; C = 256; bx = i & 7; by = i >> 3; }
        else if (b < 320) { int i = b - 256; src = rho_W1; dst = w1rt; R = 256; C = 256; bx = i & 7; by = i >> 3; }
        else              { int i = b - 320; int z = i >> 6; i &= 63;
                            src = out_W1 + (size_t)z * HH * HH; dst = whT + (size_t)z * HH * HH;
                            R = 256; C = 256; bx = i & 7; by = i >> 3; }
        const int tx = t & 31, ty = t >> 5;
        const int r0 = by * 32, c0 = bx * 32;
#pragma unroll
        for (int k = 0; k < 4; k++)
            sT[ty + k * 8][tx] = f2bf_(scl * src[(size_t)(r0 + ty + k * 8) * C + c0 + tx]);
        __syncthreads();
#pragma unroll
        for (int k = 0; k < 4; k++)
            dst[(size_t)(c0 + ty + k * 8) * R + r0 + tx] = sT[tx][ty + k * 8];
    } else if (b < 544) {
        const int idx = (b - 512) * 256 + t;
        const int c = idx >> 5, k = idx & 31;
        unsigned short v = 0;
        if (k < FR) v = f2bf_(phi_W0[k * HH + c]);
        else if (k >= 16 && k < 16 + FR) v = f2bf_(phi_W0[(k - 16) * HH + c]);
        w0pT[idx] = v;
    } else {
        const int n4 = (2 * V * HH + 2 * V) / 4;
        float4 z = {0.f, 0.f, 0.f, 0.f};
        for (int i = (b - 544) * 256 + t; i < n4; i += 1024 * 256)
            ((float4*)zbase)[i] = z;
    }
}

// ---------------------------------------------------------------------------
// Kernel A: fused phi MLP + segment sum/count. UNCHANGED from r14 (110 us,
// VGPR=64, 2 blocks/CU). Do not disturb: 64 arch VGPR + 64 acc = exactly
// the 128-reg boundary for 4 waves/SIMD.
// ---------------------------------------------------------------------------
__global__ __launch_bounds__(512, 4) void phi_seg_kernel(
    const float* __restrict__ reads,
    const int* __restrict__ ref_ids, const int* __restrict__ alt_ids,
    const unsigned short* __restrict__ w0pT, const float* __restrict__ b0,
    const unsigned short* __restrict__ w1t, const float* __restrict__ b1,
    float* __restrict__ ref_sums, float* __restrict__ alt_sums,
    int* __restrict__ ref_cnt, int* __restrict__ alt_cnt)
{
    __shared__ __align__(16) unsigned short sH[TILE_R * HPITCH];   // 67584 B
    __shared__ __align__(16) unsigned short sRB[TILE_R * RBPITCH]; // 10240 B

    const int t    = threadIdx.x;
    const int wv   = t >> 6;      // 0..7
    const int lane = t & 63;
    const int lrow = lane & 15;
    const int quad = lane >> 4;
    const int r0 = blockIdx.x * TILE_R;
    const bool is_ref = (r0 < NREF);
    const int* seg_ids = is_ref ? ref_ids : alt_ids;
    const int sbase    = is_ref ? r0 : (r0 - NREF);
    float* sums = is_ref ? ref_sums : alt_sums;
    int*   cnts = is_ref ? ref_cnt  : alt_cnt;

    // ---- stage reads: coalesced float4 -> LDS raw (overlaid on sH), then
    //      per-lane pack into sRB (hi/lo bf16 split: cols 0..10 hi, 16..26 lo)
    {
        float* raw = (float*)sH;   // 1408 floats = 5632 B; dead before GEMM1
        if (lane < 44) {
            const float4 v = *(const float4*)(reads + (size_t)(r0 + wv * 16) * FR + lane * 4);
            *(float4*)&raw[wv * 176 + lane * 4] = v;
        }
        const int lr = lane >> 2;        // local row 0..15
        const int q  = lane & 3;         // quadrant
        const float* rp = raw + (wv * 16 + lr) * FR;
        unsigned int pk0 = 0, pk1 = 0, pk2 = 0, pk3 = 0;
        if (q == 0) {
            pk0 = pk2bf_(rp[0], rp[1]); pk1 = pk2bf_(rp[2], rp[3]);
            pk2 = pk2bf_(rp[4], rp[5]); pk3 = pk2bf_(rp[6], rp[7]);
        } else if (q == 1) {
            pk0 = pk2bf_(rp[8], rp[9]); pk1 = pk2bf_(rp[10], 0.0f);
        } else if (q == 2) {
            unsigned int h01 = pk2bf_(rp[0], rp[1]);
            unsigned int h23 = pk2bf_(rp[2], rp[3]);
            unsigned int h45 = pk2bf_(rp[4], rp[5]);
            unsigned int h67 = pk2bf_(rp[6], rp[7]);
            pk0 = pk2bf_(rp[0] - lo16f_(h01), rp[1] - hi16f_(h01));
            pk1 = pk2bf_(rp[2] - lo16f_(h23), rp[3] - hi16f_(h23));
            pk2 = pk2bf_(rp[4] - lo16f_(h45), rp[5] - hi16f_(h45));
            pk3 = pk2bf_(rp[6] - lo16f_(h67), rp[7] - hi16f_(h67));
        } else {
            unsigned int h89 = pk2bf_(rp[8], rp[9]);
            unsigned int hA  = pk2bf_(rp[10], 0.0f);
            pk0 = pk2bf_(rp[8] - lo16f_(h89), rp[9] - hi16f_(h89));
            pk1 = pk2bf_(rp[10] - lo16f_(hA), 0.0f);
        }
        uint4 pkk; pkk.x = pk0; pkk.y = pk1; pkk.z = pk2; pkk.w = pk3;
        *(uint4*)&sRB[(wv * 16 + lr) * RBPITCH + q * 8] = pkk;
    }
    __syncthreads();   // B1

    // ---- GEMM1 via MFMA: wave owns H-cols [wv*32, wv*32+32); N = 128 reads.
    //      Bias folded into the C-operand (single K=32 MFMA per tile).
    {
        bf16x8 br[8];
#pragma unroll
        for (int rt = 0; rt < 8; rt++)
            br[rt] = *(const bf16x8*)&sRB[(rt * 16 + lrow) * RBPITCH + quad * 8];

#pragma unroll
        for (int cm = 0; cm < 2; cm++) {
            const bf16x8 aw = *(const bf16x8*)(w0pT + ((wv * 32 + cm * 16 + lrow) << 5) + quad * 8);
            const float4 b4 = *(const float4*)(b0 + wv * 32 + cm * 16 + quad * 4);
            const f32x4 cini = {b4.x, b4.y, b4.z, b4.w};
            f32x4 c1[8];
#pragma unroll
            for (int rt = 0; rt < 8; rt++)
                c1[rt] = __builtin_amdgcn_mfma_f32_16x16x32_bf16(aw, br[rt], cini, 0, 0, 0);

#pragma unroll
            for (int rt = 0; rt < 8; rt++) {
                const int r = rt * 16 + lrow;
                uint2 pk;
                pk.x = pk2bf_(lrelu_(c1[rt][0]), lrelu_(c1[rt][1]));
                pk.y = pk2bf_(lrelu_(c1[rt][2]), lrelu_(c1[rt][3]));
                *(uint2*)&sH[r * HPITCH + wv * 32 + cm * 16 + quad * 4] = pk;
            }
        }
    }
    __syncthreads();   // B2

    // ---- GEMM2 via MFMA: 128 reads x 32 cols per wave; acc starts at
    //      -log2e * b1 (w1t pre-scaled by -log2e in prep) ----
    f32x4 acc[8][2];
    {
        const float nb0 = NLOG2E * b1[wv * 32 + lrow];
        const float nb1 = NLOG2E * b1[wv * 32 + 16 + lrow];
#pragma unroll
        for (int mt = 0; mt < 8; mt++) {
            acc[mt][0] = (f32x4){nb0, nb0, nb0, nb0};
            acc[mt][1] = (f32x4){nb1, nb1, nb1, nb1};
        }
    }

#pragma unroll
    for (int kk = 0; kk < 8; kk++) {
        const bf16x8 bn0 = *(const bf16x8*)(w1t + (size_t)(wv * 32 + lrow) * HH + kk * 32 + quad * 8);
        const bf16x8 bn1 = *(const bf16x8*)(w1t + (size_t)(wv * 32 + 16 + lrow) * HH + kk * 32 + quad * 8);
#pragma unroll
        for (int mt = 0; mt < 8; mt++) {
            const bf16x8 am = *(const bf16x8*)&sH[(mt * 16 + lrow) * HPITCH + kk * 32 + quad * 8];
            acc[mt][0] = __builtin_amdgcn_mfma_f32_16x16x32_bf16(am, bn0, acc[mt][0], 0, 0, 0);
            acc[mt][1] = __builtin_amdgcn_mfma_f32_16x16x32_bf16(am, bn1, acc[mt][1], 0, 0, 0);
        }
    }

    // ---- sigmoid in regs: acc holds -x*log2e, so sigma = rcp(1 + 2^acc) ----
#pragma unroll
    for (int nt = 0; nt < 2; nt++)
#pragma unroll
        for (int mt = 0; mt < 8; mt++)
#pragma unroll
            for (int r = 0; r < 4; r++)
                acc[mt][nt][r] = __builtin_amdgcn_rcpf(
                    1.0f + __builtin_amdgcn_exp2f(acc[mt][nt][r]));

    // ---- ballot-driven run-compressed segment reduction, 2 row-groups ----
#pragma unroll
    for (int g = 0; g < 2; g++) {
        const int myseg = seg_ids[sbase + g * 64 + lane];
        const int prev  = __shfl_up(myseg, 1);
        const bool flag = (lane == 0) || (myseg != prev);
        unsigned long long m = __ballot(flag);

        while (m) {
            const int start = (int)__builtin_ctzll(m);
            const unsigned long long m2 = m & (m - 1);
            const int end = m2 ? (int)__builtin_ctzll(m2) : 64;
            m = m2;
            const int seg = __shfl(myseg, start);
            const unsigned len = (unsigned)(end - start);
            float* srow = sums + (size_t)seg * HH + wv * 32;

            float msk[4][4];
#pragma unroll
            for (int lm = 0; lm < 4; lm++)
#pragma unroll
                for (int r = 0; r < 4; r++) {
                    const int lrw = lm * 16 + quad * 4 + r;   // row within group
                    msk[lm][r] = ((unsigned)(lrw - start) < len) ? 1.0f : 0.0f;
                }
#pragma unroll
            for (int nt = 0; nt < 2; nt++) {
                float s = 0.f;
#pragma unroll
                for (int lm = 0; lm < 4; lm++)
#pragma unroll
                    for (int r = 0; r < 4; r++)
                        s = fmaf(acc[g * 4 + lm][nt][r], msk[lm][r], s);
                s += __shfl_down(s, 32);
                s += __shfl_down(s, 16);
                if (quad == 0)
                    atomicAdd(&srow[nt * 16 + lrow], s);
            }
            if (t == 0) atomicAdd(&cnts[seg], end - start);
        }
    }
}

// ---------------------------------------------------------------------------
// Kernel B: fused MFMA chain. r15: TILE_V=16, 512 threads, 512 blocks ->
// 2 blocks/CU co-residency (LDS ~27 KB, launch_bounds(512,4) caps regs at
// 128). Wave wv owns cols [wv*32, wv*32+32) via nt in {0,1}; single
// 16-variant M-tile. Same total MFMA work; barrier/latency stalls in one
// block now overlap the other block's compute.
// ---------------------------------------------------------------------------
__global__ __launch_bounds__(512, 4) void rho_mfma_kernel(
    const float* __restrict__ info, const int* __restrict__ vtypes,
    const float* __restrict__ om_W0, const float* __restrict__ om_b0,
    const unsigned short* __restrict__ w0t, const float* __restrict__ rho_b0,
    const unsigned short* __restrict__ w1rt, const float* __restrict__ rho_b1,
    const unsigned short* __restrict__ whT, const float* __restrict__ out_b1,
    const float* __restrict__ out_W2, const float* __restrict__ out_b2,
    const float* __restrict__ conf, const float* __restrict__ max_logit,
    const float* __restrict__ ref_sums, const float* __restrict__ alt_sums,
    const int* __restrict__ ref_cnt, const int* __restrict__ alt_cnt,
    float* __restrict__ out)
{
    __shared__ __align__(16) unsigned short sC[TILE_V * CPITCH];   // 24832 B
    __shared__ __align__(16) float sInfo[TILE_V][12];
    __shared__ float sRinvR[TILE_V], sRinvA[TILE_V];
    __shared__ float sPart[8][3][TILE_V];

    unsigned short* sA1  = sC;
    unsigned short* sAgg = sC + TILE_V * APITCH;

    const int t  = threadIdx.x;
    const int v0 = blockIdx.x * TILE_V;

    if (t < TILE_V) {
        sRinvR[t] = __builtin_amdgcn_rcpf(fmaxf((float)ref_cnt[v0 + t], 1.0f));
        sRinvA[t] = __builtin_amdgcn_rcpf(fmaxf((float)alt_cnt[v0 + t], 1.0f));
    }
    for (int idx = t; idx < TILE_V * FI; idx += 512) {
        int i = idx / FI, k = idx - i * FI;
        sInfo[i][k] = info[(size_t)(v0 + i) * FI + k];
    }
    __syncthreads();

    {
        const int c = t & 255, grp = t >> 8;   // grp = 0..1, 8 variants each
        float om0r[FI];
#pragma unroll
        for (int k = 0; k < FI; k++) om0r[k] = om_W0[k * HH + c];
        const float omb = om_b0[c];
#pragma unroll
        for (int ii = 0; ii < 8; ii++) {
            const int i = grp * 8 + ii, v = v0 + i;
            float rm = ref_sums[(size_t)v * HH + c] * sRinvR[i];
            float am = alt_sums[(size_t)v * HH + c] * sRinvA[i];
            float a = omb;
#pragma unroll
            for (int k = 0; k < FI; k++) a = fmaf(sInfo[i][k], om0r[k], a);
            sC[i * CPITCH + c]          = f2bf_(rm);
            sC[i * CPITCH + HH + c]     = f2bf_(am);
            sC[i * CPITCH + 2 * HH + c] = f2bf_(sigmoidf_(a));
        }
    }
    __syncthreads();

    const int wv   = t >> 6;      // 0..7
    const int lane = t & 63;
    const int lrow = lane & 15;
    const int quad = lane >> 4;
    const int nc0  = wv * 32 + lrow;        // nt=0 col
    const int nc1  = wv * 32 + 16 + lrow;   // nt=1 col

    f32x4 p1[2] = {(f32x4){0.f,0.f,0.f,0.f}, (f32x4){0.f,0.f,0.f,0.f}};
#pragma unroll 4
    for (int kk = 0; kk < 24; kk++) {
        bf16x8 a0 = *(const bf16x8*)&sC[lrow * CPITCH + kk * 32 + quad * 8];
        bf16x8 b0 = *(const bf16x8*)(w0t + (size_t)nc0 * 768 + kk * 32 + quad * 8);
        bf16x8 b1 = *(const bf16x8*)(w0t + (size_t)nc1 * 768 + kk * 32 + quad * 8);
        p1[0] = __builtin_amdgcn_mfma_f32_16x16x32_bf16(a0, b0, p1[0], 0, 0, 0);
        p1[1] = __builtin_amdgcn_mfma_f32_16x16x32_bf16(a0, b1, p1[1], 0, 0, 0);
    }
    __syncthreads();
    {
        const float bb0 = rho_b0[nc0];
        const float bb1 = rho_b0[nc1];
#pragma unroll
        for (int r = 0; r < 4; r++) {
            const int row = quad * 4 + r;   // variant row 0..15
            sA1[row * APITCH + nc0] = f2bf_(lrelu_(p1[0][r] + bb0));
            sA1[row * APITCH + nc1] = f2bf_(lrelu_(p1[1][r] + bb1));
        }
    }
    __syncthreads();

    f32x4 p2[2] = {(f32x4){0.f,0.f,0.f,0.f}, (f32x4){0.f,0.f,0.f,0.f}};
#pragma unroll
    for (int kk = 0; kk < 8; kk++) {
        bf16x8 a0 = *(const bf16x8*)&sA1[lrow * APITCH + kk * 32 + quad * 8];
        bf16x8 b0 = *(const bf16x8*)(w1rt + (size_t)nc0 * HH + kk * 32 + quad * 8);
        bf16x8 b1 = *(const bf16x8*)(w1rt + (size_t)nc1 * HH + kk * 32 + quad * 8);
        p2[0] = __builtin_amdgcn_mfma_f32_16x16x32_bf16(a0, b0, p2[0], 0, 0, 0);
        p2[1] = __builtin_amdgcn_mfma_f32_16x16x32_bf16(a0, b1, p2[1], 0, 0, 0);
    }
    {
        const float bb0 = rho_b1[nc0];
        const float bb1 = rho_b1[nc1];
#pragma unroll
        for (int r = 0; r < 4; r++) {
            const int row = quad * 4 + r;
            sAgg[row * APITCH + nc0] = f2bf_(p2[0][r] + bb0);
            sAgg[row * APITCH + nc1] = f2bf_(p2[1][r] + bb1);
        }
    }
    __syncthreads();

    bf16x8 aF[8];
#pragma unroll
    for (int kk = 0; kk < 8; kk++)
        aF[kk] = *(const bf16x8*)&sAgg[lrow * APITCH + kk * 32 + quad * 8];

    for (int h = 0; h < 3; h++) {
        f32x4 p3[2] = {(f32x4){0.f,0.f,0.f,0.f}, (f32x4){0.f,0.f,0.f,0.f}};
#pragma unroll
        for (int kk = 0; kk < 8; kk++) {
            bf16x8 b0 = *(const bf16x8*)(whT + ((size_t)h * HH + nc0) * HH + kk * 32 + quad * 8);
            bf16x8 b1 = *(const bf16x8*)(whT + ((size_t)h * HH + nc1) * HH + kk * 32 + quad * 8);
            p3[0] = __builtin_amdgcn_mfma_f32_16x16x32_bf16(aF[kk], b0, p3[0], 0, 0, 0);
            p3[1] = __builtin_amdgcn_mfma_f32_16x16x32_bf16(aF[kk], b1, p3[1], 0, 0, 0);
        }
        const float bb0 = out_b1[h * HH + nc0];
        const float bb1 = out_b1[h * HH + nc1];
        const float w20 = out_W2[h * HH + nc0];
        const float w21 = out_W2[h * HH + nc1];
#pragma unroll
        for (int r = 0; r < 4; r++) {
            float v = lrelu_(p3[0][r] + bb0) * w20 + lrelu_(p3[1][r] + bb1) * w21;
            v += __shfl_down(v, 8);
            v += __shfl_down(v, 4);
            v += __shfl_down(v, 2);
            v += __shfl_down(v, 1);
            if (lrow == 0) sPart[wv][h][quad * 4 + r] = v;
        }
    }
    __syncthreads();

    if (t < TILE_V) {
        const int v = v0 + t;
        const int ty = vtypes[v];
        float logit = 0.f;
#pragma unroll
        for (int w = 0; w < 8; w++) logit += sPart[w][ty][t];
        logit += out_b2[ty];
        const int tr = min(alt_cnt[v], MAX_ALT);
        logit *= conf[tr];
        const float ml = max_logit[0];
        out[v] = ml * tanhf(logit / ml);
    }
}

// ---------------------------------------------------------------------------
extern "C" void kernel_launch(void* const* d_in, const int* in_sizes, int n_in,
                              void* d_out, int out_size, void* d_ws, size_t ws_size,
                              hipStream_t stream) {
    const float* reads    = (const float*)d_in[0];
    const float* info     = (const float*)d_in[1];
    const int*   ref_ids  = (const int*)d_in[2];
    const int*   alt_ids  = (const int*)d_in[3];
    const int*   vtypes   = (const int*)d_in[4];
    const float* phi_W0   = (const float*)d_in[5];
    const float* phi_b0   = (const float*)d_in[6];
    const float* phi_W1   = (const float*)d_in[7];
    const float* phi_b1   = (const float*)d_in[8];
    const float* om_W0    = (const float*)d_in[9];
    const float* om_b0    = (const float*)d_in[10];
    const float* rho_W0   = (const float*)d_in[11];
    const float* rho_b0   = (const float*)d_in[12];
    const float* rho_W1   = (const float*)d_in[13];
    const float* rho_b1   = (const float*)d_in[14];
    const float* out_W1   = (const float*)d_in[15];
    const float* out_b1   = (const float*)d_in[16];
    const float* out_W2   = (const float*)d_in[17];
    const float* out_b2   = (const float*)d_in[18];
    const float* conf     = (const float*)d_in[19];
    const float* max_lg   = (const float*)d_in[20];
    float* out = (float*)d_out;

    float* ref_sums = (float*)d_ws;
    float* alt_sums = ref_sums + (size_t)V * HH;
    int*   ref_cnt  = (int*)(alt_sums + (size_t)V * HH);
    int*   alt_cnt  = ref_cnt + V;
    unsigned short* w1t_phi = (unsigned short*)(alt_cnt + V);
    unsigned short* w0t     = w1t_phi + (size_t)HH * HH;
    unsigned short* w1rt    = w0t + (size_t)HH * 768;
    unsigned short* whT     = w1rt + (size_t)HH * HH;
    unsigned short* w0pT    = whT + (size_t)3 * HH * HH;

    prep_kernel<<<1568, 256, 0, stream>>>(phi_W1, rho_W0, rho_W1, out_W1, phi_W0,
                                          w1t_phi, w0t, w1rt, whT, w0pT,
                                          (float*)d_ws);

    phi_seg_kernel<<<NREADS / TILE_R, 512, 0, stream>>>(
        reads, ref_ids, alt_ids, w0pT, phi_b0, w1t_phi, phi_b1,
        ref_sums, alt_sums, ref_cnt, alt_cnt);

    rho_mfma_kernel<<<V / TILE_V, 512, 0, stream>>>(
        info, vtypes, om_W0, om_b0, w0t, rho_b0, w1rt, rho_b1,
        whT, out_b1, out_W2, out_b2, conf, max_lg,
        ref_sums, alt_sums, ref_cnt, alt_cnt, out);
}

// Round 4
// 213.125 us; speedup vs baseline: 1.1822x; 1.1822x over previous
//
#include <hip/hip_runtime.h>
#include <hip/hip_bf16.h>
#include <cmath>

#define V 8192
#define NREF 262144
#define NALT 131072
#define NREADS (NREF + NALT)
#define FR 11
#define FI 9
#define HH 256
#define MAX_ALT 10

#define TILE_R 128   // phi rows per block
#define TILE_V 32    // rho variants per block (r14 best config restored)

#define HPITCH 264   // sH pitch (shorts): 528 B rows, 16B-aligned
#define RBPITCH 40   // sRB pitch (shorts)
#define CPITCH 776   // sC pitch (shorts)
#define APITCH 264   // sA1/sAgg pitch

typedef short bf16x8 __attribute__((ext_vector_type(8)));
typedef float f32x4  __attribute__((ext_vector_type(4)));

#define NLOG2E (-1.442695041f)

__device__ __forceinline__ float sigmoidf_(float x) {
    return __builtin_amdgcn_rcpf(1.0f + __expf(-x));
}
__device__ __forceinline__ float lrelu_(float x) {
    return fmaxf(x, 0.01f * x);
}
__device__ __forceinline__ unsigned short f2bf_(float f) {
    unsigned int u = __float_as_uint(f);
    u += 0x7FFFu + ((u >> 16) & 1u);
    return (unsigned short)(u >> 16);
}
__device__ __forceinline__ float bf2f_(unsigned short b) {
    return __uint_as_float(((unsigned int)b) << 16);
}
__device__ __forceinline__ unsigned int pk2bf_(float a, float b) {
    union { __hip_bfloat162 h2; unsigned int u; } cvt;
    cvt.h2 = __float22bfloat162_rn(make_float2(a, b));
    return cvt.u;
}
__device__ __forceinline__ float lo16f_(unsigned int u) {   // bf16 in low 16 -> f32
    return __uint_as_float(u << 16);
}
__device__ __forceinline__ float hi16f_(unsigned int u) {   // bf16 in high 16 -> f32
    return __uint_as_float(u & 0xFFFF0000u);
}

// ---------------------------------------------------------------------------
// Fused prep. r16: weights are written in WAVE-CONSUMPTION ORDER so the
// GEMM B-operand loads in phi/rho are contiguous 1KB per wave per k-step
// (1 txn-group instead of 16 strided 64B txns):
//   mode 0 (w1t_phi, phi 8-wave):  chunk = (kk*8 + wv)*2 + cm
//   mode 1 (w0t/w1rt/whT, rho 16-wave): chunk = kk*16 + wv
//   off = chunk*512 + lrow*32 + rem   (shorts; kk = kv>>5, rem = kv&31)
// w1t_phi additionally pre-scaled by -log2(e) for the exp2 sigmoid.
// ---------------------------------------------------------------------------
__global__ __launch_bounds__(256) void prep_kernel(
    const float* __restrict__ phi_W1, const float* __restrict__ rho_W0,
    const float* __restrict__ rho_W1, const float* __restrict__ out_W1,
    const float* __restrict__ phi_W0,
    unsigned short* __restrict__ w1t_phi, unsigned short* __restrict__ w0t,
    unsigned short* __restrict__ w1rt, unsigned short* __restrict__ whT,
    unsigned short* __restrict__ w0pT, float* __restrict__ zbase)
{
    __shared__ unsigned short sT[32][33];
    const int b = blockIdx.x;
    const int t = threadIdx.x;
    if (b < 512) {
        const float* src; unsigned short* dst; int C, bx, by, mode;
        float scl = 1.0f;
        if (b < 64)       { src = phi_W1; dst = w1t_phi; C = 256; bx = b & 7; by = b >> 3; scl = NLOG2E; mode = 0; }
        else if (b < 256) { int i = b - 64;  src = rho_W0; dst = w0t;  C = 256; bx = i & 7; by = i >> 3; mode = 1; }
        else if (b < 320) { int i = b - 256; src = rho_W1; dst = w1rt; C = 256; bx = i & 7; by = i >> 3; mode = 1; }
        else              { int i = b - 320; int z = i >> 6; i &= 63;
                            src = out_W1 + (size_t)z * HH * HH; dst = whT + (size_t)z * HH * HH;
                            C = 256; bx = i & 7; by = i >> 3; mode = 1; }
        const int tx = t & 31, ty = t >> 5;
        const int r0 = by * 32, c0 = bx * 32;
#pragma unroll
        for (int k = 0; k < 4; k++)
            sT[ty + k * 8][tx] = f2bf_(scl * src[(size_t)(r0 + ty + k * 8) * C + c0 + tx]);
        __syncthreads();
        const int kv  = r0 + tx;
        const int kk  = kv >> 5;
        const int rem = kv & 31;
#pragma unroll
        for (int k = 0; k < 4; k++) {
            const int n = c0 + ty + k * 8;   // output-neuron column
            int chunk;
            if (mode == 0) chunk = (kk * 8 + (n >> 5)) * 2 + ((n >> 4) & 1);
            else           chunk = kk * 16 + (n >> 4);
            dst[(size_t)chunk * 512 + (n & 15) * 32 + rem] = sT[tx][ty + k * 8];
        }
    } else if (b < 544) {
        const int idx = (b - 512) * 256 + t;
        const int c = idx >> 5, k = idx & 31;
        unsigned short v = 0;
        if (k < FR) v = f2bf_(phi_W0[k * HH + c]);
        else if (k >= 16 && k < 16 + FR) v = f2bf_(phi_W0[(k - 16) * HH + c]);
        w0pT[idx] = v;
    } else {
        const int n4 = (2 * V * HH + 2 * V) / 4;
        float4 z = {0.f, 0.f, 0.f, 0.f};
        for (int i = (b - 544) * 256 + t; i < n4; i += 1024 * 256)
            ((float4*)zbase)[i] = z;
    }
}

// ---------------------------------------------------------------------------
// Kernel A: fused phi MLP + segment sum/count. Identical to r14 (110 us,
// VGPR=64, 2 blocks/CU) EXCEPT GEMM2's w1t loads use the wave-order layout
// (contiguous 1KB per wave per kk). 64 arch VGPR + 64 acc = 128-reg boundary
// for 4 waves/SIMD — do not disturb.
// ---------------------------------------------------------------------------
__global__ __launch_bounds__(512, 4) void phi_seg_kernel(
    const float* __restrict__ reads,
    const int* __restrict__ ref_ids, const int* __restrict__ alt_ids,
    const unsigned short* __restrict__ w0pT, const float* __restrict__ b0,
    const unsigned short* __restrict__ w1t, const float* __restrict__ b1,
    float* __restrict__ ref_sums, float* __restrict__ alt_sums,
    int* __restrict__ ref_cnt, int* __restrict__ alt_cnt)
{
    __shared__ __align__(16) unsigned short sH[TILE_R * HPITCH];   // 67584 B
    __shared__ __align__(16) unsigned short sRB[TILE_R * RBPITCH]; // 10240 B

    const int t    = threadIdx.x;
    const int wv   = t >> 6;      // 0..7
    const int lane = t & 63;
    const int lrow = lane & 15;
    const int quad = lane >> 4;
    const int r0 = blockIdx.x * TILE_R;
    const bool is_ref = (r0 < NREF);
    const int* seg_ids = is_ref ? ref_ids : alt_ids;
    const int sbase    = is_ref ? r0 : (r0 - NREF);
    float* sums = is_ref ? ref_sums : alt_sums;
    int*   cnts = is_ref ? ref_cnt  : alt_cnt;

    // ---- stage reads: coalesced float4 -> LDS raw (overlaid on sH), then
    //      per-lane pack into sRB (hi/lo bf16 split: cols 0..10 hi, 16..26 lo)
    {
        float* raw = (float*)sH;   // 1408 floats = 5632 B; dead before GEMM1
        if (lane < 44) {
            const float4 v = *(const float4*)(reads + (size_t)(r0 + wv * 16) * FR + lane * 4);
            *(float4*)&raw[wv * 176 + lane * 4] = v;
        }
        const int lr = lane >> 2;        // local row 0..15
        const int q  = lane & 3;         // quadrant
        const float* rp = raw + (wv * 16 + lr) * FR;
        unsigned int pk0 = 0, pk1 = 0, pk2 = 0, pk3 = 0;
        if (q == 0) {
            pk0 = pk2bf_(rp[0], rp[1]); pk1 = pk2bf_(rp[2], rp[3]);
            pk2 = pk2bf_(rp[4], rp[5]); pk3 = pk2bf_(rp[6], rp[7]);
        } else if (q == 1) {
            pk0 = pk2bf_(rp[8], rp[9]); pk1 = pk2bf_(rp[10], 0.0f);
        } else if (q == 2) {
            unsigned int h01 = pk2bf_(rp[0], rp[1]);
            unsigned int h23 = pk2bf_(rp[2], rp[3]);
            unsigned int h45 = pk2bf_(rp[4], rp[5]);
            unsigned int h67 = pk2bf_(rp[6], rp[7]);
            pk0 = pk2bf_(rp[0] - lo16f_(h01), rp[1] - hi16f_(h01));
            pk1 = pk2bf_(rp[2] - lo16f_(h23), rp[3] - hi16f_(h23));
            pk2 = pk2bf_(rp[4] - lo16f_(h45), rp[5] - hi16f_(h45));
            pk3 = pk2bf_(rp[6] - lo16f_(h67), rp[7] - hi16f_(h67));
        } else {
            unsigned int h89 = pk2bf_(rp[8], rp[9]);
            unsigned int hA  = pk2bf_(rp[10], 0.0f);
            pk0 = pk2bf_(rp[8] - lo16f_(h89), rp[9] - hi16f_(h89));
            pk1 = pk2bf_(rp[10] - lo16f_(hA), 0.0f);
        }
        uint4 pkk; pkk.x = pk0; pkk.y = pk1; pkk.z = pk2; pkk.w = pk3;
        *(uint4*)&sRB[(wv * 16 + lr) * RBPITCH + q * 8] = pkk;
    }
    __syncthreads();   // B1

    // ---- GEMM1 via MFMA: wave owns H-cols [wv*32, wv*32+32); N = 128 reads.
    //      Bias folded into the C-operand (single K=32 MFMA per tile).
    {
        bf16x8 br[8];
#pragma unroll
        for (int rt = 0; rt < 8; rt++)
            br[rt] = *(const bf16x8*)&sRB[(rt * 16 + lrow) * RBPITCH + quad * 8];

#pragma unroll
        for (int cm = 0; cm < 2; cm++) {
            const bf16x8 aw = *(const bf16x8*)(w0pT + ((wv * 32 + cm * 16 + lrow) << 5) + quad * 8);
            const float4 b4 = *(const float4*)(b0 + wv * 32 + cm * 16 + quad * 4);
            const f32x4 cini = {b4.x, b4.y, b4.z, b4.w};
            f32x4 c1[8];
#pragma unroll
            for (int rt = 0; rt < 8; rt++)
                c1[rt] = __builtin_amdgcn_mfma_f32_16x16x32_bf16(aw, br[rt], cini, 0, 0, 0);

#pragma unroll
            for (int rt = 0; rt < 8; rt++) {
                const int r = rt * 16 + lrow;
                uint2 pk;
                pk.x = pk2bf_(lrelu_(c1[rt][0]), lrelu_(c1[rt][1]));
                pk.y = pk2bf_(lrelu_(c1[rt][2]), lrelu_(c1[rt][3]));
                *(uint2*)&sH[r * HPITCH + wv * 32 + cm * 16 + quad * 4] = pk;
            }
        }
    }
    __syncthreads();   // B2

    // ---- GEMM2 via MFMA: 128 reads x 32 cols per wave; acc starts at
    //      -log2e * b1 (w1t pre-scaled by -log2e in prep). Wave-order B. ----
    f32x4 acc[8][2];
    {
        const float nb0 = NLOG2E * b1[wv * 32 + lrow];
        const float nb1 = NLOG2E * b1[wv * 32 + 16 + lrow];
#pragma unroll
        for (int mt = 0; mt < 8; mt++) {
            acc[mt][0] = (f32x4){nb0, nb0, nb0, nb0};
            acc[mt][1] = (f32x4){nb1, nb1, nb1, nb1};
        }
    }

#pragma unroll
    for (int kk = 0; kk < 8; kk++) {
        const unsigned short* wb = w1t + (size_t)(kk * 8 + wv) * 1024 + lrow * 32 + quad * 8;
        const bf16x8 bn0 = *(const bf16x8*)(wb);
        const bf16x8 bn1 = *(const bf16x8*)(wb + 512);
#pragma unroll
        for (int mt = 0; mt < 8; mt++) {
            const bf16x8 am = *(const bf16x8*)&sH[(mt * 16 + lrow) * HPITCH + kk * 32 + quad * 8];
            acc[mt][0] = __builtin_amdgcn_mfma_f32_16x16x32_bf16(am, bn0, acc[mt][0], 0, 0, 0);
            acc[mt][1] = __builtin_amdgcn_mfma_f32_16x16x32_bf16(am, bn1, acc[mt][1], 0, 0, 0);
        }
    }

    // ---- sigmoid in regs: acc holds -x*log2e, so sigma = rcp(1 + 2^acc) ----
#pragma unroll
    for (int nt = 0; nt < 2; nt++)
#pragma unroll
        for (int mt = 0; mt < 8; mt++)
#pragma unroll
            for (int r = 0; r < 4; r++)
                acc[mt][nt][r] = __builtin_amdgcn_rcpf(
                    1.0f + __builtin_amdgcn_exp2f(acc[mt][nt][r]));

    // ---- ballot-driven run-compressed segment reduction, 2 row-groups ----
#pragma unroll
    for (int g = 0; g < 2; g++) {
        const int myseg = seg_ids[sbase + g * 64 + lane];
        const int prev  = __shfl_up(myseg, 1);
        const bool flag = (lane == 0) || (myseg != prev);
        unsigned long long m = __ballot(flag);

        while (m) {
            const int start = (int)__builtin_ctzll(m);
            const unsigned long long m2 = m & (m - 1);
            const int end = m2 ? (int)__builtin_ctzll(m2) : 64;
            m = m2;
            const int seg = __shfl(myseg, start);
            const unsigned len = (unsigned)(end - start);
            float* srow = sums + (size_t)seg * HH + wv * 32;

            float msk[4][4];
#pragma unroll
            for (int lm = 0; lm < 4; lm++)
#pragma unroll
                for (int r = 0; r < 4; r++) {
                    const int lrw = lm * 16 + quad * 4 + r;   // row within group
                    msk[lm][r] = ((unsigned)(lrw - start) < len) ? 1.0f : 0.0f;
                }
#pragma unroll
            for (int nt = 0; nt < 2; nt++) {
                float s = 0.f;
#pragma unroll
                for (int lm = 0; lm < 4; lm++)
#pragma unroll
                    for (int r = 0; r < 4; r++)
                        s = fmaf(acc[g * 4 + lm][nt][r], msk[lm][r], s);
                s += __shfl_down(s, 32);
                s += __shfl_down(s, 16);
                if (quad == 0)
                    atomicAdd(&srow[nt * 16 + lrow], s);
            }
            if (t == 0) atomicAdd(&cnts[seg], end - start);
        }
    }
}

// ---------------------------------------------------------------------------
// Kernel B: fused MFMA chain — r14 structure (TILE_V=32, 1024 thr, 256
// blocks; best measured) with wave-order weight loads: per kk each wave
// reads ONE contiguous 1KB chunk instead of 16 strided 64B txns.
// ---------------------------------------------------------------------------
__global__ __launch_bounds__(1024, 1) void rho_mfma_kernel(
    const float* __restrict__ info, const int* __restrict__ vtypes,
    const float* __restrict__ om_W0, const float* __restrict__ om_b0,
    const unsigned short* __restrict__ w0t, const float* __restrict__ rho_b0,
    const unsigned short* __restrict__ w1rt, const float* __restrict__ rho_b1,
    const unsigned short* __restrict__ whT, const float* __restrict__ out_b1,
    const float* __restrict__ out_W2, const float* __restrict__ out_b2,
    const float* __restrict__ conf, const float* __restrict__ max_logit,
    const float* __restrict__ ref_sums, const float* __restrict__ alt_sums,
    const int* __restrict__ ref_cnt, const int* __restrict__ alt_cnt,
    float* __restrict__ out)
{
    __shared__ __align__(16) unsigned short sC[TILE_V * CPITCH];
    __shared__ __align__(16) float sInfo[TILE_V][12];
    __shared__ float sRinvR[TILE_V], sRinvA[TILE_V];
    __shared__ float sPart[16][3][TILE_V];

    unsigned short* sA1  = sC;
    unsigned short* sAgg = sC + TILE_V * APITCH;

    const int t  = threadIdx.x;
    const int v0 = blockIdx.x * TILE_V;

    if (t < TILE_V) {
        sRinvR[t] = __builtin_amdgcn_rcpf(fmaxf((float)ref_cnt[v0 + t], 1.0f));
        sRinvA[t] = __builtin_amdgcn_rcpf(fmaxf((float)alt_cnt[v0 + t], 1.0f));
    }
    for (int idx = t; idx < TILE_V * FI; idx += 1024) {
        int i = idx / FI, k = idx - i * FI;
        sInfo[i][k] = info[(size_t)(v0 + i) * FI + k];
    }
    __syncthreads();

    {
        const int c = t & 255, grp = t >> 8;
        float om0r[FI];
#pragma unroll
        for (int k = 0; k < FI; k++) om0r[k] = om_W0[k * HH + c];
        const float omb = om_b0[c];
#pragma unroll
        for (int ii = 0; ii < 8; ii++) {
            const int i = grp * 8 + ii, v = v0 + i;
            float rm = ref_sums[(size_t)v * HH + c] * sRinvR[i];
            float am = alt_sums[(size_t)v * HH + c] * sRinvA[i];
            float a = omb;
#pragma unroll
            for (int k = 0; k < FI; k++) a = fmaf(sInfo[i][k], om0r[k], a);
            sC[i * CPITCH + c]          = f2bf_(rm);
            sC[i * CPITCH + HH + c]     = f2bf_(am);
            sC[i * CPITCH + 2 * HH + c] = f2bf_(sigmoidf_(a));
        }
    }
    __syncthreads();

    const int wv   = t >> 6;      // 0..15
    const int lane = t & 63;
    const int lrow = lane & 15;
    const int quad = lane >> 4;
    const int ncol = wv * 16 + lrow;

    f32x4 p1[2] = {(f32x4){0.f,0.f,0.f,0.f}, (f32x4){0.f,0.f,0.f,0.f}};
#pragma unroll 4
    for (int kk = 0; kk < 24; kk++) {
        bf16x8 a0 = *(const bf16x8*)&sC[lrow * CPITCH + kk * 32 + quad * 8];
        bf16x8 a1 = *(const bf16x8*)&sC[(16 + lrow) * CPITCH + kk * 32 + quad * 8];
        bf16x8 bn = *(const bf16x8*)(w0t + (size_t)(kk * 16 + wv) * 512 + lrow * 32 + quad * 8);
        p1[0] = __builtin_amdgcn_mfma_f32_16x16x32_bf16(a0, bn, p1[0], 0, 0, 0);
        p1[1] = __builtin_amdgcn_mfma_f32_16x16x32_bf16(a1, bn, p1[1], 0, 0, 0);
    }
    __syncthreads();
    {
        const float bb = rho_b0[ncol];
#pragma unroll
        for (int mt = 0; mt < 2; mt++)
#pragma unroll
            for (int r = 0; r < 4; r++) {
                const int row = mt * 16 + quad * 4 + r;
                sA1[row * APITCH + ncol] = f2bf_(lrelu_(p1[mt][r] + bb));
            }
    }
    __syncthreads();

    f32x4 p2[2] = {(f32x4){0.f,0.f,0.f,0.f}, (f32x4){0.f,0.f,0.f,0.f}};
#pragma unroll
    for (int kk = 0; kk < 8; kk++) {
        bf16x8 a0 = *(const bf16x8*)&sA1[lrow * APITCH + kk * 32 + quad * 8];
        bf16x8 a1 = *(const bf16x8*)&sA1[(16 + lrow) * APITCH + kk * 32 + quad * 8];
        bf16x8 bn = *(const bf16x8*)(w1rt + (size_t)(kk * 16 + wv) * 512 + lrow * 32 + quad * 8);
        p2[0] = __builtin_amdgcn_mfma_f32_16x16x32_bf16(a0, bn, p2[0], 0, 0, 0);
        p2[1] = __builtin_amdgcn_mfma_f32_16x16x32_bf16(a1, bn, p2[1], 0, 0, 0);
    }
    {
        const float bb = rho_b1[ncol];
#pragma unroll
        for (int mt = 0; mt < 2; mt++)
#pragma unroll
            for (int r = 0; r < 4; r++) {
                const int row = mt * 16 + quad * 4 + r;
                sAgg[row * APITCH + ncol] = f2bf_(p2[mt][r] + bb);
            }
    }
    __syncthreads();

    bf16x8 aF[8][2];
#pragma unroll
    for (int kk = 0; kk < 8; kk++)
#pragma unroll
        for (int mt = 0; mt < 2; mt++)
            aF[kk][mt] = *(const bf16x8*)&sAgg[(mt * 16 + lrow) * APITCH + kk * 32 + quad * 8];

    for (int h = 0; h < 3; h++) {
        f32x4 p3[2] = {(f32x4){0.f,0.f,0.f,0.f}, (f32x4){0.f,0.f,0.f,0.f}};
#pragma unroll
        for (int kk = 0; kk < 8; kk++) {
            bf16x8 bn = *(const bf16x8*)(whT + (size_t)h * 65536 + (size_t)(kk * 16 + wv) * 512 + lrow * 32 + quad * 8);
            p3[0] = __builtin_amdgcn_mfma_f32_16x16x32_bf16(aF[kk][0], bn, p3[0], 0, 0, 0);
            p3[1] = __builtin_amdgcn_mfma_f32_16x16x32_bf16(aF[kk][1], bn, p3[1], 0, 0, 0);
        }
        const float bb = out_b1[h * HH + ncol];
        const float w2 = out_W2[h * HH + ncol];
#pragma unroll
        for (int mt = 0; mt < 2; mt++)
#pragma unroll
            for (int r = 0; r < 4; r++) {
                float v = lrelu_(p3[mt][r] + bb) * w2;
                v += __shfl_down(v, 8);
                v += __shfl_down(v, 4);
                v += __shfl_down(v, 2);
                v += __shfl_down(v, 1);
                if (lrow == 0) sPart[wv][h][mt * 16 + quad * 4 + r] = v;
            }
    }
    __syncthreads();

    if (t < TILE_V) {
        const int v = v0 + t;
        const int ty = vtypes[v];
        float logit = 0.f;
#pragma unroll
        for (int w = 0; w < 16; w++) logit += sPart[w][ty][t];
        logit += out_b2[ty];
        const int tr = min(alt_cnt[v], MAX_ALT);
        logit *= conf[tr];
        const float ml = max_logit[0];
        out[v] = ml * tanhf(logit / ml);
    }
}

// ---------------------------------------------------------------------------
extern "C" void kernel_launch(void* const* d_in, const int* in_sizes, int n_in,
                              void* d_out, int out_size, void* d_ws, size_t ws_size,
                              hipStream_t stream) {
    const float* reads    = (const float*)d_in[0];
    const float* info     = (const float*)d_in[1];
    const int*   ref_ids  = (const int*)d_in[2];
    const int*   alt_ids  = (const int*)d_in[3];
    const int*   vtypes   = (const int*)d_in[4];
    const float* phi_W0   = (const float*)d_in[5];
    const float* phi_b0   = (const float*)d_in[6];
    const float* phi_W1   = (const float*)d_in[7];
    const float* phi_b1   = (const float*)d_in[8];
    const float* om_W0    = (const float*)d_in[9];
    const float* om_b0    = (const float*)d_in[10];
    const float* rho_W0   = (const float*)d_in[11];
    const float* rho_b0   = (const float*)d_in[12];
    const float* rho_W1   = (const float*)d_in[13];
    const float* rho_b1   = (const float*)d_in[14];
    const float* out_W1   = (const float*)d_in[15];
    const float* out_b1   = (const float*)d_in[16];
    const float* out_W2   = (const float*)d_in[17];
    const float* out_b2   = (const float*)d_in[18];
    const float* conf     = (const float*)d_in[19];
    const float* max_lg   = (const float*)d_in[20];
    float* out = (float*)d_out;

    float* ref_sums = (float*)d_ws;
    float* alt_sums = ref_sums + (size_t)V * HH;
    int*   ref_cnt  = (int*)(alt_sums + (size_t)V * HH);
    int*   alt_cnt  = ref_cnt + V;
    unsigned short* w1t_phi = (unsigned short*)(alt_cnt + V);
    unsigned short* w0t     = w1t_phi + (size_t)HH * HH;
    unsigned short* w1rt    = w0t + (size_t)HH * 768;
    unsigned short* whT     = w1rt + (size_t)HH * HH;
    unsigned short* w0pT    = whT + (size_t)3 * HH * HH;

    prep_kernel<<<1568, 256, 0, stream>>>(phi_W1, rho_W0, rho_W1, out_W1, phi_W0,
                                          w1t_phi, w0t, w1rt, whT, w0pT,
                                          (float*)d_ws);

    phi_seg_kernel<<<NREADS / TILE_R, 512, 0, stream>>>(
        reads, ref_ids, alt_ids, w0pT, phi_b0, w1t_phi, phi_b1,
        ref_sums, alt_sums, ref_cnt, alt_cnt);

    rho_mfma_kernel<<<V / TILE_V, 1024, 0, stream>>>(
        info, vtypes, om_W0, om_b0, w0t, rho_b0, w1rt, rho_b1,
        whT, out_b1, out_W2, out_b2, conf, max_lg,
        ref_sums, alt_sums, ref_cnt, alt_cnt, out);
}

// Round 5
// 212.888 us; speedup vs baseline: 1.1835x; 1.0011x over previous
//
#include <hip/hip_runtime.h>
#include <hip/hip_bf16.h>
#include <cmath>

#define V 8192
#define NREF 262144
#define NALT 131072
#define NREADS (NREF + NALT)
#define FR 11
#define FI 9
#define HH 256
#define MAX_ALT 10

#define TILE_R 128   // phi rows per block
#define TILE_V 32    // rho variants per block

#define HPITCH 264   // sH pitch (shorts): 528 B rows, 16B-aligned
#define RBPITCH 40   // sRB pitch (shorts)
#define CPITCH 776   // sC pitch (shorts)
#define APITCH 264   // sA1/sAgg pitch

typedef short bf16x8 __attribute__((ext_vector_type(8)));
typedef float f32x4  __attribute__((ext_vector_type(4)));

#define NLOG2E (-1.442695041f)

__device__ __forceinline__ float sigmoidf_(float x) {
    return __builtin_amdgcn_rcpf(1.0f + __expf(-x));
}
__device__ __forceinline__ float lrelu_(float x) {
    return fmaxf(x, 0.01f * x);
}
__device__ __forceinline__ unsigned short f2bf_(float f) {
    unsigned int u = __float_as_uint(f);
    u += 0x7FFFu + ((u >> 16) & 1u);
    return (unsigned short)(u >> 16);
}
__device__ __forceinline__ float bf2f_(unsigned short b) {
    return __uint_as_float(((unsigned int)b) << 16);
}
__device__ __forceinline__ unsigned int pk2bf_(float a, float b) {
    union { __hip_bfloat162 h2; unsigned int u; } cvt;
    cvt.h2 = __float22bfloat162_rn(make_float2(a, b));
    return cvt.u;
}
__device__ __forceinline__ float lo16f_(unsigned int u) {   // bf16 in low 16 -> f32
    return __uint_as_float(u << 16);
}
__device__ __forceinline__ float hi16f_(unsigned int u) {   // bf16 in high 16 -> f32
    return __uint_as_float(u & 0xFFFF0000u);
}

// ---------------------------------------------------------------------------
// Fused prep (unchanged from r16). Weights written in WAVE-CONSUMPTION ORDER:
//   mode 0 (w1t_phi, phi 8-wave):  chunk = (kk*8 + wv)*2 + cm
//   mode 1 (w0t/w1rt/whT, rho 16-wave): chunk = kk*16 + wv
//   off = chunk*512 + lrow*32 + rem   (shorts; kk = kv>>5, rem = kv&31)
// w1t_phi additionally pre-scaled by -log2(e) for the exp2 sigmoid.
// ---------------------------------------------------------------------------
__global__ __launch_bounds__(256) void prep_kernel(
    const float* __restrict__ phi_W1, const float* __restrict__ rho_W0,
    const float* __restrict__ rho_W1, const float* __restrict__ out_W1,
    const float* __restrict__ phi_W0,
    unsigned short* __restrict__ w1t_phi, unsigned short* __restrict__ w0t,
    unsigned short* __restrict__ w1rt, unsigned short* __restrict__ whT,
    unsigned short* __restrict__ w0pT, float* __restrict__ zbase)
{
    __shared__ unsigned short sT[32][33];
    const int b = blockIdx.x;
    const int t = threadIdx.x;
    if (b < 512) {
        const float* src; unsigned short* dst; int C, bx, by, mode;
        float scl = 1.0f;
        if (b < 64)       { src = phi_W1; dst = w1t_phi; C = 256; bx = b & 7; by = b >> 3; scl = NLOG2E; mode = 0; }
        else if (b < 256) { int i = b - 64;  src = rho_W0; dst = w0t;  C = 256; bx = i & 7; by = i >> 3; mode = 1; }
        else if (b < 320) { int i = b - 256; src = rho_W1; dst = w1rt; C = 256; bx = i & 7; by = i >> 3; mode = 1; }
        else              { int i = b - 320; int z = i >> 6; i &= 63;
                            src = out_W1 + (size_t)z * HH * HH; dst = whT + (size_t)z * HH * HH;
                            C = 256; bx = i & 7; by = i >> 3; mode = 1; }
        const int tx = t & 31, ty = t >> 5;
        const int r0 = by * 32, c0 = bx * 32;
#pragma unroll
        for (int k = 0; k < 4; k++)
            sT[ty + k * 8][tx] = f2bf_(scl * src[(size_t)(r0 + ty + k * 8) * C + c0 + tx]);
        __syncthreads();
        const int kv  = r0 + tx;
        const int kk  = kv >> 5;
        const int rem = kv & 31;
#pragma unroll
        for (int k = 0; k < 4; k++) {
            const int n = c0 + ty + k * 8;   // output-neuron column
            int chunk;
            if (mode == 0) chunk = (kk * 8 + (n >> 5)) * 2 + ((n >> 4) & 1);
            else           chunk = kk * 16 + (n >> 4);
            dst[(size_t)chunk * 512 + (n & 15) * 32 + rem] = sT[tx][ty + k * 8];
        }
    } else if (b < 544) {
        const int idx = (b - 512) * 256 + t;
        const int c = idx >> 5, k = idx & 31;
        unsigned short v = 0;
        if (k < FR) v = f2bf_(phi_W0[k * HH + c]);
        else if (k >= 16 && k < 16 + FR) v = f2bf_(phi_W0[(k - 16) * HH + c]);
        w0pT[idx] = v;
    } else {
        const int n4 = (2 * V * HH + 2 * V) / 4;
        float4 z = {0.f, 0.f, 0.f, 0.f};
        for (int i = (b - 544) * 256 + t; i < n4; i += 1024 * 256)
            ((float4*)zbase)[i] = z;
    }
}

// ---------------------------------------------------------------------------
// Kernel A: fused phi MLP + segment sum/count. BYTE-IDENTICAL to r16
// (103-105 us, VGPR=64, 2 blocks/CU). 64 arch VGPR + 64 acc AGPR = exactly
// the 128-reg / 4-waves-per-SIMD boundary; LDS 77.8KB x2 = 155/160 KB.
// Double-capped — do not add ANY live state.
// ---------------------------------------------------------------------------
__global__ __launch_bounds__(512, 4) void phi_seg_kernel(
    const float* __restrict__ reads,
    const int* __restrict__ ref_ids, const int* __restrict__ alt_ids,
    const unsigned short* __restrict__ w0pT, const float* __restrict__ b0,
    const unsigned short* __restrict__ w1t, const float* __restrict__ b1,
    float* __restrict__ ref_sums, float* __restrict__ alt_sums,
    int* __restrict__ ref_cnt, int* __restrict__ alt_cnt)
{
    __shared__ __align__(16) unsigned short sH[TILE_R * HPITCH];   // 67584 B
    __shared__ __align__(16) unsigned short sRB[TILE_R * RBPITCH]; // 10240 B

    const int t    = threadIdx.x;
    const int wv   = t >> 6;      // 0..7
    const int lane = t & 63;
    const int lrow = lane & 15;
    const int quad = lane >> 4;
    const int r0 = blockIdx.x * TILE_R;
    const bool is_ref = (r0 < NREF);
    const int* seg_ids = is_ref ? ref_ids : alt_ids;
    const int sbase    = is_ref ? r0 : (r0 - NREF);
    float* sums = is_ref ? ref_sums : alt_sums;
    int*   cnts = is_ref ? ref_cnt  : alt_cnt;

    // ---- stage reads: coalesced float4 -> LDS raw (overlaid on sH), then
    //      per-lane pack into sRB (hi/lo bf16 split: cols 0..10 hi, 16..26 lo)
    {
        float* raw = (float*)sH;   // 1408 floats = 5632 B; dead before GEMM1
        if (lane < 44) {
            const float4 v = *(const float4*)(reads + (size_t)(r0 + wv * 16) * FR + lane * 4);
            *(float4*)&raw[wv * 176 + lane * 4] = v;
        }
        const int lr = lane >> 2;        // local row 0..15
        const int q  = lane & 3;         // quadrant
        const float* rp = raw + (wv * 16 + lr) * FR;
        unsigned int pk0 = 0, pk1 = 0, pk2 = 0, pk3 = 0;
        if (q == 0) {
            pk0 = pk2bf_(rp[0], rp[1]); pk1 = pk2bf_(rp[2], rp[3]);
            pk2 = pk2bf_(rp[4], rp[5]); pk3 = pk2bf_(rp[6], rp[7]);
        } else if (q == 1) {
            pk0 = pk2bf_(rp[8], rp[9]); pk1 = pk2bf_(rp[10], 0.0f);
        } else if (q == 2) {
            unsigned int h01 = pk2bf_(rp[0], rp[1]);
            unsigned int h23 = pk2bf_(rp[2], rp[3]);
            unsigned int h45 = pk2bf_(rp[4], rp[5]);
            unsigned int h67 = pk2bf_(rp[6], rp[7]);
            pk0 = pk2bf_(rp[0] - lo16f_(h01), rp[1] - hi16f_(h01));
            pk1 = pk2bf_(rp[2] - lo16f_(h23), rp[3] - hi16f_(h23));
            pk2 = pk2bf_(rp[4] - lo16f_(h45), rp[5] - hi16f_(h45));
            pk3 = pk2bf_(rp[6] - lo16f_(h67), rp[7] - hi16f_(h67));
        } else {
            unsigned int h89 = pk2bf_(rp[8], rp[9]);
            unsigned int hA  = pk2bf_(rp[10], 0.0f);
            pk0 = pk2bf_(rp[8] - lo16f_(h89), rp[9] - hi16f_(h89));
            pk1 = pk2bf_(rp[10] - lo16f_(hA), 0.0f);
        }
        uint4 pkk; pkk.x = pk0; pkk.y = pk1; pkk.z = pk2; pkk.w = pk3;
        *(uint4*)&sRB[(wv * 16 + lr) * RBPITCH + q * 8] = pkk;
    }
    __syncthreads();   // B1

    // ---- GEMM1 via MFMA: wave owns H-cols [wv*32, wv*32+32); N = 128 reads.
    //      Bias folded into the C-operand (single K=32 MFMA per tile).
    {
        bf16x8 br[8];
#pragma unroll
        for (int rt = 0; rt < 8; rt++)
            br[rt] = *(const bf16x8*)&sRB[(rt * 16 + lrow) * RBPITCH + quad * 8];

#pragma unroll
        for (int cm = 0; cm < 2; cm++) {
            const bf16x8 aw = *(const bf16x8*)(w0pT + ((wv * 32 + cm * 16 + lrow) << 5) + quad * 8);
            const float4 b4 = *(const float4*)(b0 + wv * 32 + cm * 16 + quad * 4);
            const f32x4 cini = {b4.x, b4.y, b4.z, b4.w};
            f32x4 c1[8];
#pragma unroll
            for (int rt = 0; rt < 8; rt++)
                c1[rt] = __builtin_amdgcn_mfma_f32_16x16x32_bf16(aw, br[rt], cini, 0, 0, 0);

#pragma unroll
            for (int rt = 0; rt < 8; rt++) {
                const int r = rt * 16 + lrow;
                uint2 pk;
                pk.x = pk2bf_(lrelu_(c1[rt][0]), lrelu_(c1[rt][1]));
                pk.y = pk2bf_(lrelu_(c1[rt][2]), lrelu_(c1[rt][3]));
                *(uint2*)&sH[r * HPITCH + wv * 32 + cm * 16 + quad * 4] = pk;
            }
        }
    }
    __syncthreads();   // B2

    // ---- GEMM2 via MFMA: 128 reads x 32 cols per wave; acc starts at
    //      -log2e * b1 (w1t pre-scaled by -log2e in prep). Wave-order B. ----
    f32x4 acc[8][2];
    {
        const float nb0 = NLOG2E * b1[wv * 32 + lrow];
        const float nb1 = NLOG2E * b1[wv * 32 + 16 + lrow];
#pragma unroll
        for (int mt = 0; mt < 8; mt++) {
            acc[mt][0] = (f32x4){nb0, nb0, nb0, nb0};
            acc[mt][1] = (f32x4){nb1, nb1, nb1, nb1};
        }
    }

#pragma unroll
    for (int kk = 0; kk < 8; kk++) {
        const unsigned short* wb = w1t + (size_t)(kk * 8 + wv) * 1024 + lrow * 32 + quad * 8;
        const bf16x8 bn0 = *(const bf16x8*)(wb);
        const bf16x8 bn1 = *(const bf16x8*)(wb + 512);
#pragma unroll
        for (int mt = 0; mt < 8; mt++) {
            const bf16x8 am = *(const bf16x8*)&sH[(mt * 16 + lrow) * HPITCH + kk * 32 + quad * 8];
            acc[mt][0] = __builtin_amdgcn_mfma_f32_16x16x32_bf16(am, bn0, acc[mt][0], 0, 0, 0);
            acc[mt][1] = __builtin_amdgcn_mfma_f32_16x16x32_bf16(am, bn1, acc[mt][1], 0, 0, 0);
        }
    }

    // ---- sigmoid in regs: acc holds -x*log2e, so sigma = rcp(1 + 2^acc) ----
#pragma unroll
    for (int nt = 0; nt < 2; nt++)
#pragma unroll
        for (int mt = 0; mt < 8; mt++)
#pragma unroll
            for (int r = 0; r < 4; r++)
                acc[mt][nt][r] = __builtin_amdgcn_rcpf(
                    1.0f + __builtin_amdgcn_exp2f(acc[mt][nt][r]));

    // ---- ballot-driven run-compressed segment reduction, 2 row-groups ----
#pragma unroll
    for (int g = 0; g < 2; g++) {
        const int myseg = seg_ids[sbase + g * 64 + lane];
        const int prev  = __shfl_up(myseg, 1);
        const bool flag = (lane == 0) || (myseg != prev);
        unsigned long long m = __ballot(flag);

        while (m) {
            const int start = (int)__builtin_ctzll(m);
            const unsigned long long m2 = m & (m - 1);
            const int end = m2 ? (int)__builtin_ctzll(m2) : 64;
            m = m2;
            const int seg = __shfl(myseg, start);
            const unsigned len = (unsigned)(end - start);
            float* srow = sums + (size_t)seg * HH + wv * 32;

            float msk[4][4];
#pragma unroll
            for (int lm = 0; lm < 4; lm++)
#pragma unroll
                for (int r = 0; r < 4; r++) {
                    const int lrw = lm * 16 + quad * 4 + r;   // row within group
                    msk[lm][r] = ((unsigned)(lrw - start) < len) ? 1.0f : 0.0f;
                }
#pragma unroll
            for (int nt = 0; nt < 2; nt++) {
                float s = 0.f;
#pragma unroll
                for (int lm = 0; lm < 4; lm++)
#pragma unroll
                    for (int r = 0; r < 4; r++)
                        s = fmaf(acc[g * 4 + lm][nt][r], msk[lm][r], s);
                s += __shfl_down(s, 32);
                s += __shfl_down(s, 16);
                if (quad == 0)
                    atomicAdd(&srow[nt * 16 + lrow], s);
            }
            if (t == 0) atomicAdd(&cnts[seg], end - start);
        }
    }
}

// ---------------------------------------------------------------------------
// Kernel B: fused MFMA chain. r17: cross-phase register prefetch —
// GEMM1's kk=0..7 weight chunks load at kernel entry (latency hidden under
// the means phase); GEMM2's chunks load between GEMM1's halves (hidden
// under 32 MFMAs + barrier). Peak live regs ~124 <= 128 cap (1024-thread
// block forces 4 waves/SIMD). Layout/structure otherwise r16.
// ---------------------------------------------------------------------------
__global__ __launch_bounds__(1024, 1) void rho_mfma_kernel(
    const float* __restrict__ info, const int* __restrict__ vtypes,
    const float* __restrict__ om_W0, const float* __restrict__ om_b0,
    const unsigned short* __restrict__ w0t, const float* __restrict__ rho_b0,
    const unsigned short* __restrict__ w1rt, const float* __restrict__ rho_b1,
    const unsigned short* __restrict__ whT, const float* __restrict__ out_b1,
    const float* __restrict__ out_W2, const float* __restrict__ out_b2,
    const float* __restrict__ conf, const float* __restrict__ max_logit,
    const float* __restrict__ ref_sums, const float* __restrict__ alt_sums,
    const int* __restrict__ ref_cnt, const int* __restrict__ alt_cnt,
    float* __restrict__ out)
{
    __shared__ __align__(16) unsigned short sC[TILE_V * CPITCH];
    __shared__ __align__(16) float sInfo[TILE_V][12];
    __shared__ float sRinvR[TILE_V], sRinvA[TILE_V];
    __shared__ float sPart[16][3][TILE_V];

    unsigned short* sA1  = sC;
    unsigned short* sAgg = sC + TILE_V * APITCH;

    const int t  = threadIdx.x;
    const int v0 = blockIdx.x * TILE_V;
    const int wv   = t >> 6;      // 0..15
    const int lane = t & 63;
    const int lrow = lane & 15;
    const int quad = lane >> 4;
    const int ncol = wv * 16 + lrow;

    // ---- r17: prefetch GEMM1 weight chunks kk=0..7 (no deps) so the loads
    //      complete during the means phase below ----
    bf16x8 w1pre[8];
#pragma unroll
    for (int kk = 0; kk < 8; kk++)
        w1pre[kk] = *(const bf16x8*)(w0t + (size_t)(kk * 16 + wv) * 512 + lrow * 32 + quad * 8);

    if (t < TILE_V) {
        sRinvR[t] = __builtin_amdgcn_rcpf(fmaxf((float)ref_cnt[v0 + t], 1.0f));
        sRinvA[t] = __builtin_amdgcn_rcpf(fmaxf((float)alt_cnt[v0 + t], 1.0f));
    }
    for (int idx = t; idx < TILE_V * FI; idx += 1024) {
        int i = idx / FI, k = idx - i * FI;
        sInfo[i][k] = info[(size_t)(v0 + i) * FI + k];
    }
    __syncthreads();

    {
        const int c = t & 255, grp = t >> 8;
        float om0r[FI];
#pragma unroll
        for (int k = 0; k < FI; k++) om0r[k] = om_W0[k * HH + c];
        const float omb = om_b0[c];
#pragma unroll
        for (int ii = 0; ii < 8; ii++) {
            const int i = grp * 8 + ii, v = v0 + i;
            float rm = ref_sums[(size_t)v * HH + c] * sRinvR[i];
            float am = alt_sums[(size_t)v * HH + c] * sRinvA[i];
            float a = omb;
#pragma unroll
            for (int k = 0; k < FI; k++) a = fmaf(sInfo[i][k], om0r[k], a);
            sC[i * CPITCH + c]          = f2bf_(rm);
            sC[i * CPITCH + HH + c]     = f2bf_(am);
            sC[i * CPITCH + 2 * HH + c] = f2bf_(sigmoidf_(a));
        }
    }
    __syncthreads();

    // ---- GEMM1: first 8 k-steps from prefetched regs ----
    f32x4 p1[2] = {(f32x4){0.f,0.f,0.f,0.f}, (f32x4){0.f,0.f,0.f,0.f}};
#pragma unroll
    for (int kk = 0; kk < 8; kk++) {
        bf16x8 a0 = *(const bf16x8*)&sC[lrow * CPITCH + kk * 32 + quad * 8];
        bf16x8 a1 = *(const bf16x8*)&sC[(16 + lrow) * CPITCH + kk * 32 + quad * 8];
        p1[0] = __builtin_amdgcn_mfma_f32_16x16x32_bf16(a0, w1pre[kk], p1[0], 0, 0, 0);
        p1[1] = __builtin_amdgcn_mfma_f32_16x16x32_bf16(a1, w1pre[kk], p1[1], 0, 0, 0);
    }

    // ---- prefetch GEMM2 weights; latency hides under GEMM1's tail ----
    bf16x8 w2pre[8];
#pragma unroll
    for (int kk = 0; kk < 8; kk++)
        w2pre[kk] = *(const bf16x8*)(w1rt + (size_t)(kk * 16 + wv) * 512 + lrow * 32 + quad * 8);

#pragma unroll 8
    for (int kk = 8; kk < 24; kk++) {
        bf16x8 a0 = *(const bf16x8*)&sC[lrow * CPITCH + kk * 32 + quad * 8];
        bf16x8 a1 = *(const bf16x8*)&sC[(16 + lrow) * CPITCH + kk * 32 + quad * 8];
        bf16x8 bn = *(const bf16x8*)(w0t + (size_t)(kk * 16 + wv) * 512 + lrow * 32 + quad * 8);
        p1[0] = __builtin_amdgcn_mfma_f32_16x16x32_bf16(a0, bn, p1[0], 0, 0, 0);
        p1[1] = __builtin_amdgcn_mfma_f32_16x16x32_bf16(a1, bn, p1[1], 0, 0, 0);
    }
    __syncthreads();
    {
        const float bb = rho_b0[ncol];
#pragma unroll
        for (int mt = 0; mt < 2; mt++)
#pragma unroll
            for (int r = 0; r < 4; r++) {
                const int row = mt * 16 + quad * 4 + r;
                sA1[row * APITCH + ncol] = f2bf_(lrelu_(p1[mt][r] + bb));
            }
    }
    __syncthreads();

    // ---- GEMM2 from prefetched regs ----
    f32x4 p2[2] = {(f32x4){0.f,0.f,0.f,0.f}, (f32x4){0.f,0.f,0.f,0.f}};
#pragma unroll
    for (int kk = 0; kk < 8; kk++) {
        bf16x8 a0 = *(const bf16x8*)&sA1[lrow * APITCH + kk * 32 + quad * 8];
        bf16x8 a1 = *(const bf16x8*)&sA1[(16 + lrow) * APITCH + kk * 32 + quad * 8];
        p2[0] = __builtin_amdgcn_mfma_f32_16x16x32_bf16(a0, w2pre[kk], p2[0], 0, 0, 0);
        p2[1] = __builtin_amdgcn_mfma_f32_16x16x32_bf16(a1, w2pre[kk], p2[1], 0, 0, 0);
    }
    {
        const float bb = rho_b1[ncol];
#pragma unroll
        for (int mt = 0; mt < 2; mt++)
#pragma unroll
            for (int r = 0; r < 4; r++) {
                const int row = mt * 16 + quad * 4 + r;
                sAgg[row * APITCH + ncol] = f2bf_(p2[mt][r] + bb);
            }
    }
    __syncthreads();

    bf16x8 aF[8][2];
#pragma unroll
    for (int kk = 0; kk < 8; kk++)
#pragma unroll
        for (int mt = 0; mt < 2; mt++)
            aF[kk][mt] = *(const bf16x8*)&sAgg[(mt * 16 + lrow) * APITCH + kk * 32 + quad * 8];

    for (int h = 0; h < 3; h++) {
        f32x4 p3[2] = {(f32x4){0.f,0.f,0.f,0.f}, (f32x4){0.f,0.f,0.f,0.f}};
#pragma unroll
        for (int kk = 0; kk < 8; kk++) {
            bf16x8 bn = *(const bf16x8*)(whT + (size_t)h * 65536 + (size_t)(kk * 16 + wv) * 512 + lrow * 32 + quad * 8);
            p3[0] = __builtin_amdgcn_mfma_f32_16x16x32_bf16(aF[kk][0], bn, p3[0], 0, 0, 0);
            p3[1] = __builtin_amdgcn_mfma_f32_16x16x32_bf16(aF[kk][1], bn, p3[1], 0, 0, 0);
        }
        const float bb = out_b1[h * HH + ncol];
        const float w2 = out_W2[h * HH + ncol];
#pragma unroll
        for (int mt = 0; mt < 2; mt++)
#pragma unroll
            for (int r = 0; r < 4; r++) {
                float v = lrelu_(p3[mt][r] + bb) * w2;
                v += __shfl_down(v, 8);
                v += __shfl_down(v, 4);
                v += __shfl_down(v, 2);
                v += __shfl_down(v, 1);
                if (lrow == 0) sPart[wv][h][mt * 16 + quad * 4 + r] = v;
            }
    }
    __syncthreads();

    if (t < TILE_V) {
        const int v = v0 + t;
        const int ty = vtypes[v];
        float logit = 0.f;
#pragma unroll
        for (int w = 0; w < 16; w++) logit += sPart[w][ty][t];
        logit += out_b2[ty];
        const int tr = min(alt_cnt[v], MAX_ALT);
        logit *= conf[tr];
        const float ml = max_logit[0];
        out[v] = ml * tanhf(logit / ml);
    }
}

// ---------------------------------------------------------------------------
extern "C" void kernel_launch(void* const* d_in, const int* in_sizes, int n_in,
                              void* d_out, int out_size, void* d_ws, size_t ws_size,
                              hipStream_t stream) {
    const float* reads    = (const float*)d_in[0];
    const float* info     = (const float*)d_in[1];
    const int*   ref_ids  = (const int*)d_in[2];
    const int*   alt_ids  = (const int*)d_in[3];
    const int*   vtypes   = (const int*)d_in[4];
    const float* phi_W0   = (const float*)d_in[5];
    const float* phi_b0   = (const float*)d_in[6];
    const float* phi_W1   = (const float*)d_in[7];
    const float* phi_b1   = (const float*)d_in[8];
    const float* om_W0    = (const float*)d_in[9];
    const float* om_b0    = (const float*)d_in[10];
    const float* rho_W0   = (const float*)d_in[11];
    const float* rho_b0   = (const float*)d_in[12];
    const float* rho_W1   = (const float*)d_in[13];
    const float* rho_b1   = (const float*)d_in[14];
    const float* out_W1   = (const float*)d_in[15];
    const float* out_b1   = (const float*)d_in[16];
    const float* out_W2   = (const float*)d_in[17];
    const float* out_b2   = (const float*)d_in[18];
    const float* conf     = (const float*)d_in[19];
    const float* max_lg   = (const float*)d_in[20];
    float* out = (float*)d_out;

    float* ref_sums = (float*)d_ws;
    float* alt_sums = ref_sums + (size_t)V * HH;
    int*   ref_cnt  = (int*)(alt_sums + (size_t)V * HH);
    int*   alt_cnt  = ref_cnt + V;
    unsigned short* w1t_phi = (unsigned short*)(alt_cnt + V);
    unsigned short* w0t     = w1t_phi + (size_t)HH * HH;
    unsigned short* w1rt    = w0t + (size_t)HH * 768;
    unsigned short* whT     = w1rt + (size_t)HH * HH;
    unsigned short* w0pT    = whT + (size_t)3 * HH * HH;

    prep_kernel<<<1568, 256, 0, stream>>>(phi_W1, rho_W0, rho_W1, out_W1, phi_W0,
                                          w1t_phi, w0t, w1rt, whT, w0pT,
                                          (float*)d_ws);

    phi_seg_kernel<<<NREADS / TILE_R, 512, 0, stream>>>(
        reads, ref_ids, alt_ids, w0pT, phi_b0, w1t_phi, phi_b1,
        ref_sums, alt_sums, ref_cnt, alt_cnt);

    rho_mfma_kernel<<<V / TILE_V, 1024, 0, stream>>>(
        info, vtypes, om_W0, om_b0, w0t, rho_b0, w1rt, rho_b1,
        whT, out_b1, out_W2, out_b2, conf, max_lg,
        ref_sums, alt_sums, ref_cnt, alt_cnt, out);
}